// Round 1
// baseline (537.258 us; speedup 1.0000x reference)
//
#include <hip/hip_runtime.h>

// CrossAttention: LN -> proj GEMMs -> logits GEMM -> softmax -> 2 PV GEMMs.
// All GEMMs are bf16 MFMA (16x16x32), B^T-form (both operands K-contiguous).
// Workspace layout (needs 205,520,896 B ~= 196 MiB):
//   R1 [0,      64MiB): norm_img|norm_txt  -> reused as projT_img|projT_txt
//   R2 [64MiB, 128MiB): proj_img|proj_txt  -> reused as attnT
//   WB [128MiB,132MiB): W_img|W_txt as bf16
//   R4 [132MiB,196MiB): logits bf16 -> softmax in place -> attn

#define DEV __device__ __forceinline__

typedef short s16x8 __attribute__((ext_vector_type(8)));
typedef float f32x4 __attribute__((ext_vector_type(4)));

DEV unsigned short f2bf(float f){            // fp32 -> bf16, round-nearest-even
  unsigned u = __float_as_uint(f);
  u = (u + 0x7fffu + ((u >> 16) & 1u)) >> 16;
  return (unsigned short)u;
}
DEV float bf2f(unsigned short s){ return __uint_as_float(((unsigned)s) << 16); }

DEV void ldsload16(const void* g, void* l){
  __builtin_amdgcn_global_load_lds((const __attribute__((address_space(1))) void*)g,
                                   (__attribute__((address_space(3))) void*)l, 16, 0, 0);
}

// ---------------- fp32 -> bf16 convert ----------------
__global__ __launch_bounds__(256) void k_cvt(const float* __restrict__ src,
                                             unsigned short* __restrict__ dst, int n4){
  int i = blockIdx.x * 256 + threadIdx.x;
  if (i < n4){
    float4 v = ((const float4*)src)[i];
    ushort4 o;
    o.x = f2bf(v.x); o.y = f2bf(v.y); o.z = f2bf(v.z); o.w = f2bf(v.w);
    ((ushort4*)dst)[i] = o;
  }
}

// ---------------- LayerNorm (D=1024) fp32 -> bf16 ----------------
__global__ __launch_bounds__(256) void k_ln(const float* __restrict__ x,
                                            const float* __restrict__ w,
                                            const float* __restrict__ b,
                                            unsigned short* __restrict__ y){
  int row = blockIdx.x, tid = threadIdx.x;
  float4 v = ((const float4*)(x + (size_t)row * 1024))[tid];
  float s  = v.x + v.y + v.z + v.w;
  float s2 = v.x*v.x + v.y*v.y + v.z*v.z + v.w*v.w;
  #pragma unroll
  for (int o = 32; o > 0; o >>= 1){ s += __shfl_xor(s, o, 64); s2 += __shfl_xor(s2, o, 64); }
  __shared__ float sh[8];
  int wv = tid >> 6, ln = tid & 63;
  if (!ln){ sh[wv] = s; sh[4 + wv] = s2; }
  __syncthreads();
  s  = sh[0] + sh[1] + sh[2] + sh[3];
  s2 = sh[4] + sh[5] + sh[6] + sh[7];
  float mean = s * (1.f/1024.f);
  float var  = s2 * (1.f/1024.f) - mean * mean;
  float rstd = rsqrtf(var + 1e-5f);
  float4 w4 = ((const float4*)w)[tid];
  float4 b4 = ((const float4*)b)[tid];
  ushort4 o;
  o.x = f2bf((v.x-mean)*rstd*w4.x + b4.x);
  o.y = f2bf((v.y-mean)*rstd*w4.y + b4.y);
  o.z = f2bf((v.z-mean)*rstd*w4.z + b4.z);
  o.w = f2bf((v.w-mean)*rstd*w4.w + b4.w);
  ((ushort4*)(y + (size_t)row * 1024))[tid] = o;
}

// ---------------- bf16 B^T-form GEMM ----------------
// C[m,n] = scale * sum_k A[m,k]*Bt[n,k] + bias[n]
// Tile 128x128, BK=64, 4 waves (2x2), each wave 64x64 = 4x4 mfma_16x16x32 frags.
// Staging: global_load_lds 16B with XOR-swizzled global source (LDS write is
// linear); fragment ds_read_b128 applies the same swizzle -> conflict-free.
template<int OUT_BF16>
__global__ __launch_bounds__(256) void k_gemm_bt(const unsigned short* __restrict__ A,
                                                 const unsigned short* __restrict__ Bt,
                                                 void* __restrict__ C,
                                                 const float* __restrict__ bias, float scale,
                                                 int K, int lda, int ldb, int ldc,
                                                 long sA, long sB, long sC){
  __shared__ __align__(16) unsigned short As[128 * 64];
  __shared__ __align__(16) unsigned short Bs[128 * 64];
  int tid = threadIdx.x;
  int lane = tid & 63, wave = tid >> 6;
  int wm = wave >> 1, wn = wave & 1;
  int q = lane >> 4;
  const unsigned short* Ab = A  + (size_t)blockIdx.z * sA + (size_t)blockIdx.y * 128 * lda;
  const unsigned short* Bb = Bt + (size_t)blockIdx.z * sB + (size_t)blockIdx.x * 128 * ldb;
  int srow = tid >> 3;                     // staged row (per i: + i*32)
  int u = (tid & 7) ^ (srow & 7);          // swizzled global chunk for this lane

  f32x4 acc[4][4];
  #pragma unroll
  for (int m = 0; m < 4; ++m)
    #pragma unroll
    for (int n = 0; n < 4; ++n) acc[m][n] = f32x4{0.f, 0.f, 0.f, 0.f};

  for (int t = 0; t < K; t += 64){
    #pragma unroll
    for (int i = 0; i < 4; ++i)
      ldsload16(Ab + (size_t)(i*32 + srow) * lda + t + u*8, &As[(i*256 + wave*64) * 8]);
    #pragma unroll
    for (int i = 0; i < 4; ++i)
      ldsload16(Bb + (size_t)(i*32 + srow) * ldb + t + u*8, &Bs[(i*256 + wave*64) * 8]);
    __syncthreads();   // compiler drains vmcnt before s_barrier
    #pragma unroll
    for (int kk = 0; kk < 2; ++kk){
      s16x8 af[4], bfr[4];
      #pragma unroll
      for (int m = 0; m < 4; ++m){
        int r = wm*64 + m*16 + (lane & 15);
        int p = (kk*4 + q) ^ (r & 7);
        af[m] = *(const s16x8*)&As[r*64 + p*8];
      }
      #pragma unroll
      for (int n = 0; n < 4; ++n){
        int r = wn*64 + n*16 + (lane & 15);
        int p = (kk*4 + q) ^ (r & 7);
        bfr[n] = *(const s16x8*)&Bs[r*64 + p*8];
      }
      #pragma unroll
      for (int m = 0; m < 4; ++m)
        #pragma unroll
        for (int n = 0; n < 4; ++n)
          acc[m][n] = __builtin_amdgcn_mfma_f32_16x16x32_bf16(af[m], bfr[n], acc[m][n], 0, 0, 0);
    }
    __syncthreads();
  }
  size_t cb = (size_t)blockIdx.z * sC;
  int row0 = blockIdx.y*128 + wm*64 + (lane >> 4) * 4;
  int col0 = blockIdx.x*128 + wn*64 + (lane & 15);
  #pragma unroll
  for (int m = 0; m < 4; ++m){
    #pragma unroll
    for (int n = 0; n < 4; ++n){
      int col = col0 + n*16;
      float bv = bias ? bias[col] : 0.f;
      #pragma unroll
      for (int j = 0; j < 4; ++j){
        int row = row0 + m*16 + j;
        float vv = acc[m][n][j] * scale + bv;
        if (OUT_BF16) ((unsigned short*)C)[cb + (size_t)row*ldc + col] = f2bf(vv);
        else          ((float*)C)[cb + (size_t)row*ldc + col] = vv;
      }
    }
  }
}

// ---------------- bf16 transpose, 64x64 tiles, swizzled LDS ----------------
// dst[c][r] = src[r][c]; chunk position swizzle: pos = u ^ (r&7) ^ (r>>3)
__global__ __launch_bounds__(256) void k_transpose(const unsigned short* __restrict__ src,
                                                   unsigned short* __restrict__ dst,
                                                   int R, int C, long sS, long sD){
  __shared__ __align__(16) unsigned short tile[64 * 64];
  int tid = threadIdx.x;
  const unsigned short* sb = src + (size_t)blockIdx.z * sS;
  unsigned short* db = dst + (size_t)blockIdx.z * sD;
  int r0 = blockIdx.y * 64, c0 = blockIdx.x * 64;
  #pragma unroll
  for (int i = 0; i < 2; ++i){
    int ci = i * 256 + tid;
    int row = ci >> 3, cch = ci & 7;
    int pos = cch ^ (row & 7) ^ (row >> 3);
    uint4 v = *(const uint4*)&sb[(size_t)(r0 + row) * C + c0 + cch * 8];
    *(uint4*)&tile[row * 64 + pos * 8] = v;
  }
  __syncthreads();
  int ocp = tid >> 3, og = tid & 7;
  int oc = ocp * 2;
  union { uint4 v; unsigned short us[8]; } o0, o1;
  #pragma unroll
  for (int k = 0; k < 8; ++k){
    int r = og * 8 + k;
    int pos = (oc >> 3) ^ (r & 7) ^ (r >> 3);
    unsigned pr = *(const unsigned*)&tile[r * 64 + pos * 8 + (oc & 7)];
    o0.us[k] = (unsigned short)(pr & 0xffffu);
    o1.us[k] = (unsigned short)(pr >> 16);
  }
  *(uint4*)&db[(size_t)(c0 + oc    ) * R + r0 + og * 8] = o0.v;
  *(uint4*)&db[(size_t)(c0 + oc + 1) * R + r0 + og * 8] = o1.v;
}

// ---------------- row softmax over 2048, bf16 in-place ----------------
__global__ __launch_bounds__(256) void k_softmax(unsigned short* __restrict__ a){
  size_t row = blockIdx.x;
  unsigned short* p = a + row * 2048;
  int tid = threadIdx.x;
  union { uint4 v; unsigned short us[8]; } in, out;
  in.v = *(const uint4*)&p[tid * 8];
  float x[8];
  #pragma unroll
  for (int j = 0; j < 8; ++j) x[j] = bf2f(in.us[j]);
  float mx = x[0];
  #pragma unroll
  for (int j = 1; j < 8; ++j) mx = fmaxf(mx, x[j]);
  #pragma unroll
  for (int o = 32; o > 0; o >>= 1) mx = fmaxf(mx, __shfl_xor(mx, o, 64));
  __shared__ float sh[8];
  int wv = tid >> 6, ln = tid & 63;
  if (!ln) sh[wv] = mx;
  __syncthreads();
  mx = fmaxf(fmaxf(sh[0], sh[1]), fmaxf(sh[2], sh[3]));
  float sm = 0.f, e[8];
  #pragma unroll
  for (int j = 0; j < 8; ++j){ e[j] = __expf(x[j] - mx); sm += e[j]; }
  #pragma unroll
  for (int o = 32; o > 0; o >>= 1) sm += __shfl_xor(sm, o, 64);
  if (!ln) sh[4 + wv] = sm;
  __syncthreads();
  sm = sh[4] + sh[5] + sh[6] + sh[7];
  float inv = 1.f / sm;
  #pragma unroll
  for (int j = 0; j < 8; ++j) out.us[j] = f2bf(e[j] * inv);
  *(uint4*)&p[tid * 8] = out.v;
}

extern "C" void kernel_launch(void* const* d_in, const int* in_sizes, int n_in,
                              void* d_out, int out_size, void* d_ws, size_t ws_size,
                              hipStream_t stream) {
  const float* img  = (const float*)d_in[0];   // [8,2048,1024]
  const float* txt  = (const float*)d_in[1];   // [8,2048,1024]
  const float* lnw  = (const float*)d_in[2];   // [1024]
  const float* lnb  = (const float*)d_in[3];   // [1024]
  const float* Wimg = (const float*)d_in[4];   // [1024,1024]
  const float* bimg = (const float*)d_in[5];   // [1024]
  const float* Wtxt = (const float*)d_in[6];   // [1024,1024]
  const float* btxt = (const float*)d_in[7];   // [1024]
  float* out = (float*)d_out;                  // image_out | text_out

  char* ws = (char*)d_ws;
  unsigned short* R1 = (unsigned short*)ws;                   // 33.5M elems
  unsigned short* R2 = (unsigned short*)(ws + 67108864);      // 33.5M elems
  unsigned short* WB = (unsigned short*)(ws + 134217728);     // 2x1M elems
  unsigned short* R4 = (unsigned short*)(ws + 138412032);     // 33.5M elems

  const long PB = 2097152;   // proj per-batch elems (2048*1024)
  const long AB = 4194304;   // attn per-batch elems (2048*2048)

  // W -> bf16
  k_cvt<<<1024, 256, 0, stream>>>(Wimg, WB,           262144);
  k_cvt<<<1024, 256, 0, stream>>>(Wtxt, WB + 1048576, 262144);
  // LayerNorm -> bf16 norms in R1
  k_ln<<<16384, 256, 0, stream>>>(img, lnw, lnb, R1);
  k_ln<<<16384, 256, 0, stream>>>(txt, lnw, lnb, R1 + 16777216);
  // Projections: [16384,1024] = norm @ W^T + b  -> bf16 proj in R2
  dim3 gp(8, 128, 1);
  k_gemm_bt<1><<<gp, 256, 0, stream>>>(R1,            WB,           R2,            bimg, 1.f,
                                       1024, 1024, 1024, 1024, 0, 0, 0);
  k_gemm_bt<1><<<gp, 256, 0, stream>>>(R1 + 16777216, WB + 1048576, R2 + 16777216, btxt, 1.f,
                                       1024, 1024, 1024, 1024, 0, 0, 0);
  // projT (per batch [1024][2048]) into R1 (norms dead)
  dim3 gt(16, 32, 8);
  k_transpose<<<gt, 256, 0, stream>>>(R2,            R1,            2048, 1024, PB, PB);
  k_transpose<<<gt, 256, 0, stream>>>(R2 + 16777216, R1 + 16777216, 2048, 1024, PB, PB);
  // logits[b] = proj_img[b] @ proj_txt[b]^T / 32  -> bf16 in R4
  dim3 ga(16, 16, 8);
  k_gemm_bt<1><<<ga, 256, 0, stream>>>(R2, R2 + 16777216, R4, nullptr, 0.03125f,
                                       1024, 1024, 1024, 2048, PB, PB, AB);
  // softmax rows, in place
  k_softmax<<<16384, 256, 0, stream>>>(R4);
  // attnT into R2 (proj dead)
  dim3 gat(32, 32, 8);
  k_transpose<<<gat, 256, 0, stream>>>(R4, R2, 2048, 2048, AB, AB);
  // image_out[b] = attn[b] @ txtpT[b]^T   (fp32 -> d_out)
  dim3 gpv(8, 16, 8);
  k_gemm_bt<0><<<gpv, 256, 0, stream>>>(R4, R1 + 16777216, out, nullptr, 1.f,
                                        2048, 2048, 2048, 1024, AB, PB, PB);
  // text_out[b] = attnT[b] @ imgpT[b]^T
  k_gemm_bt<0><<<gpv, 256, 0, stream>>>(R2, R1, out + 16777216, nullptr, 1.f,
                                        2048, 2048, 2048, 1024, AB, PB, PB);
}

// Round 2
// 461.531 us; speedup vs baseline: 1.1641x; 1.1641x over previous
//
#include <hip/hip_runtime.h>

// CrossAttention: LN -> proj GEMMs -> logits GEMM -> softmax -> 2 PV GEMMs.
// GEMM: 256x256 tile, BK=64, 8 waves (2Mx4N), dbuf 128KiB LDS, per-phase
// barriers + setprio (m201-style), 1-tile-deep pipelined global_load_lds
// (vmcnt(0) drain has a full tile of head start), XCD-swizzled 1D grid.
// Workspace layout (196 MiB):
//   R1 [0,      64MiB): norm_img|norm_txt  -> reused as projT_img|projT_txt
//   R2 [64MiB, 128MiB): proj_img|proj_txt  -> reused as attnT
//   WB [128MiB,132MiB): W_img|W_txt as bf16
//   R4 [132MiB,196MiB): logits bf16 -> softmax in place -> attn

#define DEV __device__ __forceinline__

typedef short s16x8 __attribute__((ext_vector_type(8)));
typedef float f32x4 __attribute__((ext_vector_type(4)));

DEV unsigned short f2bf(float f){            // fp32 -> bf16, round-nearest-even
  unsigned u = __float_as_uint(f);
  u = (u + 0x7fffu + ((u >> 16) & 1u)) >> 16;
  return (unsigned short)u;
}
DEV float bf2f(unsigned short s){ return __uint_as_float(((unsigned)s) << 16); }

DEV void ldsload16(const void* g, void* l){
  __builtin_amdgcn_global_load_lds((const __attribute__((address_space(1))) void*)g,
                                   (__attribute__((address_space(3))) void*)l, 16, 0, 0);
}

// ---------------- fp32 -> bf16 convert ----------------
__global__ __launch_bounds__(256) void k_cvt(const float* __restrict__ src,
                                             unsigned short* __restrict__ dst, int n4){
  int i = blockIdx.x * 256 + threadIdx.x;
  if (i < n4){
    float4 v = ((const float4*)src)[i];
    ushort4 o;
    o.x = f2bf(v.x); o.y = f2bf(v.y); o.z = f2bf(v.z); o.w = f2bf(v.w);
    ((ushort4*)dst)[i] = o;
  }
}

// ---------------- LayerNorm (D=1024) fp32 -> bf16 ----------------
__global__ __launch_bounds__(256) void k_ln(const float* __restrict__ x,
                                            const float* __restrict__ w,
                                            const float* __restrict__ b,
                                            unsigned short* __restrict__ y){
  int row = blockIdx.x, tid = threadIdx.x;
  float4 v = ((const float4*)(x + (size_t)row * 1024))[tid];
  float s  = v.x + v.y + v.z + v.w;
  float s2 = v.x*v.x + v.y*v.y + v.z*v.z + v.w*v.w;
  #pragma unroll
  for (int o = 32; o > 0; o >>= 1){ s += __shfl_xor(s, o, 64); s2 += __shfl_xor(s2, o, 64); }
  __shared__ float sh[8];
  int wv = tid >> 6, ln = tid & 63;
  if (!ln){ sh[wv] = s; sh[4 + wv] = s2; }
  __syncthreads();
  s  = sh[0] + sh[1] + sh[2] + sh[3];
  s2 = sh[4] + sh[5] + sh[6] + sh[7];
  float mean = s * (1.f/1024.f);
  float var  = s2 * (1.f/1024.f) - mean * mean;
  float rstd = rsqrtf(var + 1e-5f);
  float4 w4 = ((const float4*)w)[tid];
  float4 b4 = ((const float4*)b)[tid];
  ushort4 o;
  o.x = f2bf((v.x-mean)*rstd*w4.x + b4.x);
  o.y = f2bf((v.y-mean)*rstd*w4.y + b4.y);
  o.z = f2bf((v.z-mean)*rstd*w4.z + b4.z);
  o.w = f2bf((v.w-mean)*rstd*w4.w + b4.w);
  ((ushort4*)(y + (size_t)row * 1024))[tid] = o;
}

// ---------------- bf16 B^T-form GEMM, 256x256 tile, 8 waves ----------------
// C[m,n] = scale * sum_k A[m,k]*Bt[n,k] + bias[n]
// LDS tile layout: row-major [256][64] bf16 per buffer; 16B chunk p of row r
// holds global k-chunk p ^ (r&7) (conflict-free ds_read_b128, measured 0).
// Pipeline: at tile top, vmcnt(0) drains loads issued one full tile earlier;
// barrier publishes them; next tile's 8 global_load_lds issued into the buf
// freed by that barrier. 4 phases/tile: {ds_read; barrier; lgkmcnt(0);
// setprio(1); 16 MFMA; setprio(0); barrier}.
template<int OUT_BF16>
__global__ __launch_bounds__(512, 2) void k_gemm256(const unsigned short* __restrict__ A,
                                                    const unsigned short* __restrict__ Bt,
                                                    void* __restrict__ C,
                                                    const float* __restrict__ bias, float scale,
                                                    int K, int lda, int ldb, int ldc,
                                                    long sA, long sB, long sC,
                                                    int NBX, int NBY){
  __shared__ __align__(16) unsigned short As[2][256 * 64];
  __shared__ __align__(16) unsigned short Bs[2][256 * 64];
  int nwg = gridDim.x;                       // always a multiple of 8 here
  int bid = blockIdx.x;
  int swz = (bid & 7) * (nwg >> 3) + (bid >> 3);   // bijective XCD swizzle (T1)
  int bx = swz % NBX; int rem = swz / NBX;
  int by = rem % NBY; int bz = rem / NBY;

  int tid = threadIdx.x, lane = tid & 63, wave = tid >> 6;
  int wm = wave >> 2, wn = wave & 3;         // 2 x 4 wave grid
  int q = lane >> 4, fr = lane & 15;
  const unsigned short* Ab = A  + (size_t)bz * sA + (size_t)by * 256 * lda;
  const unsigned short* Bb = Bt + (size_t)bz * sB + (size_t)bx * 256 * ldb;
  int sr = tid >> 3;                         // staging row within 64-row group
  int u8 = ((tid & 7) ^ (sr & 7)) * 8;       // swizzled source k-offset (elems)
  int NT = K >> 6;

  f32x4 acc[8][4];
  #pragma unroll
  for (int m = 0; m < 8; ++m)
    #pragma unroll
    for (int n = 0; n < 4; ++n) acc[m][n] = f32x4{0.f, 0.f, 0.f, 0.f};

  // prologue: stage tile 0 -> buf 0 (8 loads/thread)
  #pragma unroll
  for (int i = 0; i < 4; ++i)
    ldsload16(Ab + (size_t)(i*64 + sr) * lda + u8, &As[0][(i*512 + wave*64) * 8]);
  #pragma unroll
  for (int i = 0; i < 4; ++i)
    ldsload16(Bb + (size_t)(i*64 + sr) * ldb + u8, &Bs[0][(i*512 + wave*64) * 8]);

  for (int t = 0; t < NT; ++t){
    int c = t & 1;
    asm volatile("s_waitcnt vmcnt(0)" ::: "memory");   // tile t landed (issued 1 tile ago)
    __builtin_amdgcn_s_barrier();                       // publish to all waves
    if (t + 1 < NT){                                    // stage tile t+1 into freed buf
      int ko = (t + 1) << 6;
      #pragma unroll
      for (int i = 0; i < 4; ++i)
        ldsload16(Ab + (size_t)(i*64 + sr) * lda + ko + u8, &As[c^1][(i*512 + wave*64) * 8]);
      #pragma unroll
      for (int i = 0; i < 4; ++i)
        ldsload16(Bb + (size_t)(i*64 + sr) * ldb + ko + u8, &Bs[c^1][(i*512 + wave*64) * 8]);
    }
    const unsigned short* Ap = As[c];
    const unsigned short* Bp = Bs[c];
    // B fragments: wave's 4 n-frags x 2 kk, held across all 4 phases (8 reads)
    s16x8 bfrag[4][2];
    #pragma unroll
    for (int n = 0; n < 4; ++n){
      int r = wn*64 + n*16 + fr;
      #pragma unroll
      for (int kk = 0; kk < 2; ++kk){
        int p = (kk*4 + q) ^ (r & 7);
        bfrag[n][kk] = *(const s16x8*)&Bp[r*64 + p*8];
      }
    }
    #pragma unroll
    for (int ph = 0; ph < 4; ++ph){
      s16x8 af[2][2];
      #pragma unroll
      for (int mm = 0; mm < 2; ++mm){
        int r = wm*128 + (ph*2 + mm)*16 + fr;
        #pragma unroll
        for (int kk = 0; kk < 2; ++kk){
          int p = (kk*4 + q) ^ (r & 7);
          af[mm][kk] = *(const s16x8*)&Ap[r*64 + p*8];
        }
      }
      __builtin_amdgcn_s_barrier();
      asm volatile("s_waitcnt lgkmcnt(0)" ::: "memory");
      __builtin_amdgcn_s_setprio(1);
      #pragma unroll
      for (int mm = 0; mm < 2; ++mm)
        #pragma unroll
        for (int n = 0; n < 4; ++n)
          #pragma unroll
          for (int kk = 0; kk < 2; ++kk)
            acc[ph*2 + mm][n] = __builtin_amdgcn_mfma_f32_16x16x32_bf16(
                af[mm][kk], bfrag[n][kk], acc[ph*2 + mm][n], 0, 0, 0);
      __builtin_amdgcn_s_setprio(0);
      __builtin_amdgcn_s_barrier();
    }
  }
  // epilogue
  size_t cb = (size_t)bz * sC;
  int row0 = by*256 + wm*128 + q*4;
  int col0 = bx*256 + wn*64 + fr;
  #pragma unroll
  for (int m = 0; m < 8; ++m){
    #pragma unroll
    for (int n = 0; n < 4; ++n){
      int col = col0 + n*16;
      float bv = bias ? bias[col] : 0.f;
      #pragma unroll
      for (int j = 0; j < 4; ++j){
        int row = row0 + m*16 + j;
        float vv = acc[m][n][j] * scale + bv;
        if (OUT_BF16) ((unsigned short*)C)[cb + (size_t)row*ldc + col] = f2bf(vv);
        else          ((float*)C)[cb + (size_t)row*ldc + col] = vv;
      }
    }
  }
}

// ---------------- bf16 transpose, 64x64 tiles, swizzled LDS ----------------
__global__ __launch_bounds__(256) void k_transpose(const unsigned short* __restrict__ src,
                                                   unsigned short* __restrict__ dst,
                                                   int R, int C, long sS, long sD){
  __shared__ __align__(16) unsigned short tile[64 * 64];
  int tid = threadIdx.x;
  const unsigned short* sb = src + (size_t)blockIdx.z * sS;
  unsigned short* db = dst + (size_t)blockIdx.z * sD;
  int r0 = blockIdx.y * 64, c0 = blockIdx.x * 64;
  #pragma unroll
  for (int i = 0; i < 2; ++i){
    int ci = i * 256 + tid;
    int row = ci >> 3, cch = ci & 7;
    int pos = cch ^ (row & 7) ^ (row >> 3);
    uint4 v = *(const uint4*)&sb[(size_t)(r0 + row) * C + c0 + cch * 8];
    *(uint4*)&tile[row * 64 + pos * 8] = v;
  }
  __syncthreads();
  int ocp = tid >> 3, og = tid & 7;
  int oc = ocp * 2;
  union { uint4 v; unsigned short us[8]; } o0, o1;
  #pragma unroll
  for (int k = 0; k < 8; ++k){
    int r = og * 8 + k;
    int pos = (oc >> 3) ^ (r & 7) ^ (r >> 3);
    unsigned pr = *(const unsigned*)&tile[r * 64 + pos * 8 + (oc & 7)];
    o0.us[k] = (unsigned short)(pr & 0xffffu);
    o1.us[k] = (unsigned short)(pr >> 16);
  }
  *(uint4*)&db[(size_t)(c0 + oc    ) * R + r0 + og * 8] = o0.v;
  *(uint4*)&db[(size_t)(c0 + oc + 1) * R + r0 + og * 8] = o1.v;
}

// ---------------- row softmax over 2048, bf16 in-place ----------------
__global__ __launch_bounds__(256) void k_softmax(unsigned short* __restrict__ a){
  size_t row = blockIdx.x;
  unsigned short* p = a + row * 2048;
  int tid = threadIdx.x;
  union { uint4 v; unsigned short us[8]; } in, out;
  in.v = *(const uint4*)&p[tid * 8];
  float x[8];
  #pragma unroll
  for (int j = 0; j < 8; ++j) x[j] = bf2f(in.us[j]);
  float mx = x[0];
  #pragma unroll
  for (int j = 1; j < 8; ++j) mx = fmaxf(mx, x[j]);
  #pragma unroll
  for (int o = 32; o > 0; o >>= 1) mx = fmaxf(mx, __shfl_xor(mx, o, 64));
  __shared__ float sh[8];
  int wv = tid >> 6, ln = tid & 63;
  if (!ln) sh[wv] = mx;
  __syncthreads();
  mx = fmaxf(fmaxf(sh[0], sh[1]), fmaxf(sh[2], sh[3]));
  float sm = 0.f, e[8];
  #pragma unroll
  for (int j = 0; j < 8; ++j){ e[j] = __expf(x[j] - mx); sm += e[j]; }
  #pragma unroll
  for (int o = 32; o > 0; o >>= 1) sm += __shfl_xor(sm, o, 64);
  if (!ln) sh[4 + wv] = sm;
  __syncthreads();
  sm = sh[4] + sh[5] + sh[6] + sh[7];
  float inv = 1.f / sm;
  #pragma unroll
  for (int j = 0; j < 8; ++j) out.us[j] = f2bf(e[j] * inv);
  *(uint4*)&p[tid * 8] = out.v;
}

extern "C" void kernel_launch(void* const* d_in, const int* in_sizes, int n_in,
                              void* d_out, int out_size, void* d_ws, size_t ws_size,
                              hipStream_t stream) {
  const float* img  = (const float*)d_in[0];   // [8,2048,1024]
  const float* txt  = (const float*)d_in[1];   // [8,2048,1024]
  const float* lnw  = (const float*)d_in[2];   // [1024]
  const float* lnb  = (const float*)d_in[3];   // [1024]
  const float* Wimg = (const float*)d_in[4];   // [1024,1024]
  const float* bimg = (const float*)d_in[5];   // [1024]
  const float* Wtxt = (const float*)d_in[6];   // [1024,1024]
  const float* btxt = (const float*)d_in[7];   // [1024]
  float* out = (float*)d_out;                  // image_out | text_out

  char* ws = (char*)d_ws;
  unsigned short* R1 = (unsigned short*)ws;                   // 33.5M elems
  unsigned short* R2 = (unsigned short*)(ws + 67108864);      // 33.5M elems
  unsigned short* WB = (unsigned short*)(ws + 134217728);     // 2x1M elems
  unsigned short* R4 = (unsigned short*)(ws + 138412032);     // 33.5M elems

  const long PB = 2097152;   // proj per-batch elems (2048*1024)
  const long AB = 4194304;   // attn per-batch elems (2048*2048)

  // W -> bf16
  k_cvt<<<1024, 256, 0, stream>>>(Wimg, WB,           262144);
  k_cvt<<<1024, 256, 0, stream>>>(Wtxt, WB + 1048576, 262144);
  // LayerNorm -> bf16 norms in R1
  k_ln<<<16384, 256, 0, stream>>>(img, lnw, lnb, R1);
  k_ln<<<16384, 256, 0, stream>>>(txt, lnw, lnb, R1 + 16777216);
  // Projections: [16384,1024] = norm @ W^T + b  -> bf16 proj in R2
  k_gemm256<1><<<256, 512, 0, stream>>>(R1,            WB,           R2,            bimg, 1.f,
                                        1024, 1024, 1024, 1024, 0, 0, 0, 4, 64);
  k_gemm256<1><<<256, 512, 0, stream>>>(R1 + 16777216, WB + 1048576, R2 + 16777216, btxt, 1.f,
                                        1024, 1024, 1024, 1024, 0, 0, 0, 4, 64);
  // projT (per batch [1024][2048]) into R1 (norms dead)
  dim3 gt(16, 32, 8);
  k_transpose<<<gt, 256, 0, stream>>>(R2,            R1,            2048, 1024, PB, PB);
  k_transpose<<<gt, 256, 0, stream>>>(R2 + 16777216, R1 + 16777216, 2048, 1024, PB, PB);
  // logits[b] = proj_img[b] @ proj_txt[b]^T / 32  -> bf16 in R4
  k_gemm256<1><<<512, 512, 0, stream>>>(R2, R2 + 16777216, R4, nullptr, 0.03125f,
                                        1024, 1024, 1024, 2048, PB, PB, AB, 8, 8);
  // softmax rows, in place
  k_softmax<<<16384, 256, 0, stream>>>(R4);
  // attnT into R2 (proj dead)
  dim3 gat(32, 32, 8);
  k_transpose<<<gat, 256, 0, stream>>>(R4, R2, 2048, 2048, AB, AB);
  // image_out[b] = attn[b] @ txtpT[b]^T   (fp32 -> d_out)
  k_gemm256<0><<<256, 512, 0, stream>>>(R4, R1 + 16777216, out, nullptr, 1.f,
                                        2048, 2048, 2048, 1024, AB, PB, PB, 4, 8);
  // text_out[b] = attnT[b] @ imgpT[b]^T
  k_gemm256<0><<<256, 512, 0, stream>>>(R2, R1, out + 16777216, nullptr, 1.f,
                                        2048, 2048, 2048, 1024, AB, PB, PB, 4, 8);
}

// Round 3
// 439.692 us; speedup vs baseline: 1.2219x; 1.0497x over previous
//
#include <hip/hip_runtime.h>

// CrossAttention: LN -> proj GEMMs -> logits GEMM -> softmax -> 2 PV GEMMs.
// GEMM: 256x256 tile, BK=64, 8 waves (2Mx4N), m201-style 8-phase schedule:
// 2 K-tiles per iteration, 1 half-tile (matrix x k-half, 2 global_load_lds)
// staged per phase 3-4 phases before consumption, counted vmcnt(4) at odd
// phase ends (never 0 in steady state), per-phase barrier + lgkmcnt(0) +
// setprio(1) around the 16-MFMA cluster. LDS [buf][khalf][256][32] with
// lane-static XOR chunk swizzle on both stage-source and read (2-way = free).
// Workspace layout (196 MiB):
//   R1 [0,      64MiB): norm_img|norm_txt  -> reused as projT_img|projT_txt
//   R2 [64MiB, 128MiB): proj_img|proj_txt  -> reused as attnT
//   WB [128MiB,132MiB): W_img|W_txt as bf16
//   R4 [132MiB,196MiB): logits bf16 -> softmax in place -> attn

#define DEV __device__ __forceinline__

typedef short s16x8 __attribute__((ext_vector_type(8)));
typedef float f32x4 __attribute__((ext_vector_type(4)));

DEV unsigned short f2bf(float f){            // fp32 -> bf16, round-nearest-even
  unsigned u = __float_as_uint(f);
  u = (u + 0x7fffu + ((u >> 16) & 1u)) >> 16;
  return (unsigned short)u;
}
DEV float bf2f(unsigned short s){ return __uint_as_float(((unsigned)s) << 16); }

DEV void ldsload16(const void* g, void* l){
  __builtin_amdgcn_global_load_lds((const __attribute__((address_space(1))) void*)g,
                                   (__attribute__((address_space(3))) void*)l, 16, 0, 0);
}

// ---------------- fp32 -> bf16 convert ----------------
__global__ __launch_bounds__(256) void k_cvt(const float* __restrict__ src,
                                             unsigned short* __restrict__ dst, int n4){
  int i = blockIdx.x * 256 + threadIdx.x;
  if (i < n4){
    float4 v = ((const float4*)src)[i];
    ushort4 o;
    o.x = f2bf(v.x); o.y = f2bf(v.y); o.z = f2bf(v.z); o.w = f2bf(v.w);
    ((ushort4*)dst)[i] = o;
  }
}

// ---------------- LayerNorm (D=1024) fp32 -> bf16 ----------------
__global__ __launch_bounds__(256) void k_ln(const float* __restrict__ x,
                                            const float* __restrict__ w,
                                            const float* __restrict__ b,
                                            unsigned short* __restrict__ y){
  int row = blockIdx.x, tid = threadIdx.x;
  float4 v = ((const float4*)(x + (size_t)row * 1024))[tid];
  float s  = v.x + v.y + v.z + v.w;
  float s2 = v.x*v.x + v.y*v.y + v.z*v.z + v.w*v.w;
  #pragma unroll
  for (int o = 32; o > 0; o >>= 1){ s += __shfl_xor(s, o, 64); s2 += __shfl_xor(s2, o, 64); }
  __shared__ float sh[8];
  int wv = tid >> 6, ln = tid & 63;
  if (!ln){ sh[wv] = s; sh[4 + wv] = s2; }
  __syncthreads();
  s  = sh[0] + sh[1] + sh[2] + sh[3];
  s2 = sh[4] + sh[5] + sh[6] + sh[7];
  float mean = s * (1.f/1024.f);
  float var  = s2 * (1.f/1024.f) - mean * mean;
  float rstd = rsqrtf(var + 1e-5f);
  float4 w4 = ((const float4*)w)[tid];
  float4 b4 = ((const float4*)b)[tid];
  ushort4 o;
  o.x = f2bf((v.x-mean)*rstd*w4.x + b4.x);
  o.y = f2bf((v.y-mean)*rstd*w4.y + b4.y);
  o.z = f2bf((v.z-mean)*rstd*w4.z + b4.z);
  o.w = f2bf((v.w-mean)*rstd*w4.w + b4.w);
  ((ushort4*)(y + (size_t)row * 1024))[tid] = o;
}

// ---------------- bf16 B^T-form GEMM, 256x256, 8-phase pipeline ----------------
// C[m,n] = scale * sum_k A[m,k]*Bt[n,k] + bias[n]
// Stage one half-tile per thread (2 loads): matrix X, k-half H of tile T.
// LDS chunk swizzle: global k-chunk g = lchunk ^ (r&3) ^ ((r>>2)&3); both the
// stage source offset and the read chunk reduce to pure lane bits.
#define STG(MAT, BASE, LD, T, H) do{                                              \
  ldsload16((BASE) + (size_t)(rl      ) * (LD) + (T)*64 + (H)*32 + g8,            \
            &MAT[(T)&1][H][(wave*16)*32]);                                        \
  ldsload16((BASE) + (size_t)(rl + 128) * (LD) + (T)*64 + (H)*32 + g8,            \
            &MAT[(T)&1][H][(128 + wave*16)*32]);                                  \
}while(0)

template<int OUT_BF16>
__global__ __launch_bounds__(512, 2) void k_gemm256(const unsigned short* __restrict__ A,
                                                    const unsigned short* __restrict__ Bt,
                                                    void* __restrict__ C,
                                                    const float* __restrict__ bias, float scale,
                                                    int K, int lda, int ldb, int ldc,
                                                    long sA, long sB, long sC,
                                                    int NBX, int NBY){
  __shared__ __align__(16) unsigned short As[2][2][8192];   // [buf][khalf][256*32]
  __shared__ __align__(16) unsigned short Bs[2][2][8192];
  int nwg = gridDim.x;                       // always a multiple of 8 here
  int bid = blockIdx.x;
  int swz = (bid & 7) * (nwg >> 3) + (bid >> 3);   // bijective XCD swizzle (T1)
  int bx = swz % NBX; int rem = swz / NBX;
  int by = rem % NBY; int bz = rem / NBY;

  int tid = threadIdx.x, lane = tid & 63, wave = tid >> 6;
  int wm = wave >> 2, wn = wave & 3;         // 2 x 4 wave grid
  int q = lane >> 4, fr = lane & 15;
  const unsigned short* Ab = A  + (size_t)bz * sA + (size_t)by * 256 * lda;
  const unsigned short* Bb = Bt + (size_t)bz * sB + (size_t)bx * 256 * ldb;
  // staging per-thread statics: row-local + swizzled source chunk (lane-static)
  int rl = wave*16 + (lane>>2);                              // 0..127 (+128 for j=1)
  int g8 = (((lane&3) ^ ((lane>>2)&3) ^ ((lane>>4)&3))) * 8; // source k-chunk offset
  // read statics: swizzled LDS chunk (lane-static, 2-way bank alias = free)
  int qp8 = ((q ^ (lane&3) ^ ((lane>>2)&3))) * 8;
  int aro = (wm*128 + fr)*32 + qp8;          // + m*512 within half
  int bro = (wn*64  + fr)*32 + qp8;          // + n*512 within half
  int NT = K >> 6, niter = K >> 7;

  f32x4 acc[8][4];
  #pragma unroll
  for (int m = 0; m < 8; ++m)
    #pragma unroll
    for (int n = 0; n < 4; ++n) acc[m][n] = f32x4{0.f, 0.f, 0.f, 0.f};

  // prologue: stage tile 0 in consumption order (Bh0, Ah0, Bh1, Ah1)
  STG(Bs, Bb, ldb, 0, 0);
  STG(As, Ab, lda, 0, 0);
  STG(Bs, Bb, ldb, 0, 1);
  STG(As, Ab, lda, 0, 1);
  asm volatile("s_waitcnt vmcnt(4)" ::: "memory");   // h0 landed; h1 in flight
  asm volatile("s_barrier" ::: "memory");

  for (int i = 0; i < niter; ++i){
    s16x8 bf[4];
    #pragma unroll
    for (int ph = 0; ph < 8; ++ph){
      const int buf = ph >> 2;               // tile 2i (buf0) then 2i+1 (buf1)
      const int kk  = (ph >> 1) & 1;
      const unsigned short* Ah = &As[buf][kk][0];
      const unsigned short* Bh = &Bs[buf][kk][0];
      s16x8 af[4];
      if ((ph & 1) == 0){                    // new k-half: B frags + A m0-3
        #pragma unroll
        for (int n = 0; n < 4; ++n) bf[n] = *(const s16x8*)&Bh[bro + n*512];
        #pragma unroll
        for (int mi = 0; mi < 4; ++mi) af[mi] = *(const s16x8*)&Ah[aro + mi*512];
      } else {                               // A m4-7
        #pragma unroll
        for (int mi = 0; mi < 4; ++mi) af[mi] = *(const s16x8*)&Ah[aro + (4+mi)*512];
      }
      { // stage 1 half-tile: phases 0-3 -> tile 2i+1, phases 4-7 -> tile 2i+2
        int tgt = 2*i + ((ph < 4) ? 1 : 2);
        if (tgt < NT){
          const int h = (ph >> 1) & 1;
          if (ph & 1) STG(As, Ab, lda, tgt, h);
          else        STG(Bs, Bb, ldb, tgt, h);
        }
      }
      asm volatile("s_barrier" ::: "memory");
      asm volatile("s_waitcnt lgkmcnt(0)" ::: "memory");
      __builtin_amdgcn_s_setprio(1);
      #pragma unroll
      for (int mi = 0; mi < 4; ++mi)
        #pragma unroll
        for (int n = 0; n < 4; ++n)
          acc[(ph&1)*4 + mi][n] = __builtin_amdgcn_mfma_f32_16x16x32_bf16(
              af[mi], bf[n], acc[(ph&1)*4 + mi][n], 0, 0, 0);
      __builtin_amdgcn_s_setprio(0);
      if (ph & 1){                            // counted fence before closing barrier
        if (i + 1 < niter || ph < 5)
          asm volatile("s_waitcnt vmcnt(4)" ::: "memory");
        else if (ph == 5)
          asm volatile("s_waitcnt vmcnt(0)" ::: "memory");  // tail: no ph4-5 stages issued
      }
      asm volatile("s_barrier" ::: "memory");
    }
  }
  // epilogue
  size_t cb = (size_t)bz * sC;
  int row0 = by*256 + wm*128 + q*4;
  int col0 = bx*256 + wn*64 + fr;
  #pragma unroll
  for (int m = 0; m < 8; ++m){
    #pragma unroll
    for (int n = 0; n < 4; ++n){
      int col = col0 + n*16;
      float bv = bias ? bias[col] : 0.f;
      #pragma unroll
      for (int j = 0; j < 4; ++j){
        int row = row0 + m*16 + j;
        float vv = acc[m][n][j] * scale + bv;
        if (OUT_BF16) ((unsigned short*)C)[cb + (size_t)row*ldc + col] = f2bf(vv);
        else          ((float*)C)[cb + (size_t)row*ldc + col] = vv;
      }
    }
  }
}

// ---------------- bf16 transpose, 64x64 tiles, swizzled LDS ----------------
__global__ __launch_bounds__(256) void k_transpose(const unsigned short* __restrict__ src,
                                                   unsigned short* __restrict__ dst,
                                                   int R, int C, long sS, long sD){
  __shared__ __align__(16) unsigned short tile[64 * 64];
  int tid = threadIdx.x;
  const unsigned short* sb = src + (size_t)blockIdx.z * sS;
  unsigned short* db = dst + (size_t)blockIdx.z * sD;
  int r0 = blockIdx.y * 64, c0 = blockIdx.x * 64;
  #pragma unroll
  for (int i = 0; i < 2; ++i){
    int ci = i * 256 + tid;
    int row = ci >> 3, cch = ci & 7;
    int pos = cch ^ (row & 7) ^ (row >> 3);
    uint4 v = *(const uint4*)&sb[(size_t)(r0 + row) * C + c0 + cch * 8];
    *(uint4*)&tile[row * 64 + pos * 8] = v;
  }
  __syncthreads();
  int ocp = tid >> 3, og = tid & 7;
  int oc = ocp * 2;
  union { uint4 v; unsigned short us[8]; } o0, o1;
  #pragma unroll
  for (int k = 0; k < 8; ++k){
    int r = og * 8 + k;
    int pos = (oc >> 3) ^ (r & 7) ^ (r >> 3);
    unsigned pr = *(const unsigned*)&tile[r * 64 + pos * 8 + (oc & 7)];
    o0.us[k] = (unsigned short)(pr & 0xffffu);
    o1.us[k] = (unsigned short)(pr >> 16);
  }
  *(uint4*)&db[(size_t)(c0 + oc    ) * R + r0 + og * 8] = o0.v;
  *(uint4*)&db[(size_t)(c0 + oc + 1) * R + r0 + og * 8] = o1.v;
}

// ---------------- row softmax over 2048, bf16 in-place ----------------
__global__ __launch_bounds__(256) void k_softmax(unsigned short* __restrict__ a){
  size_t row = blockIdx.x;
  unsigned short* p = a + row * 2048;
  int tid = threadIdx.x;
  union { uint4 v; unsigned short us[8]; } in, out;
  in.v = *(const uint4*)&p[tid * 8];
  float x[8];
  #pragma unroll
  for (int j = 0; j < 8; ++j) x[j] = bf2f(in.us[j]);
  float mx = x[0];
  #pragma unroll
  for (int j = 1; j < 8; ++j) mx = fmaxf(mx, x[j]);
  #pragma unroll
  for (int o = 32; o > 0; o >>= 1) mx = fmaxf(mx, __shfl_xor(mx, o, 64));
  __shared__ float sh[8];
  int wv = tid >> 6, ln = tid & 63;
  if (!ln) sh[wv] = mx;
  __syncthreads();
  mx = fmaxf(fmaxf(sh[0], sh[1]), fmaxf(sh[2], sh[3]));
  float sm = 0.f, e[8];
  #pragma unroll
  for (int j = 0; j < 8; ++j){ e[j] = __expf(x[j] - mx); sm += e[j]; }
  #pragma unroll
  for (int o = 32; o > 0; o >>= 1) sm += __shfl_xor(sm, o, 64);
  if (!ln) sh[4 + wv] = sm;
  __syncthreads();
  sm = sh[4] + sh[5] + sh[6] + sh[7];
  float inv = 1.f / sm;
  #pragma unroll
  for (int j = 0; j < 8; ++j) out.us[j] = f2bf(e[j] * inv);
  *(uint4*)&p[tid * 8] = out.v;
}

extern "C" void kernel_launch(void* const* d_in, const int* in_sizes, int n_in,
                              void* d_out, int out_size, void* d_ws, size_t ws_size,
                              hipStream_t stream) {
  const float* img  = (const float*)d_in[0];   // [8,2048,1024]
  const float* txt  = (const float*)d_in[1];   // [8,2048,1024]
  const float* lnw  = (const float*)d_in[2];   // [1024]
  const float* lnb  = (const float*)d_in[3];   // [1024]
  const float* Wimg = (const float*)d_in[4];   // [1024,1024]
  const float* bimg = (const float*)d_in[5];   // [1024]
  const float* Wtxt = (const float*)d_in[6];   // [1024,1024]
  const float* btxt = (const float*)d_in[7];   // [1024]
  float* out = (float*)d_out;                  // image_out | text_out

  char* ws = (char*)d_ws;
  unsigned short* R1 = (unsigned short*)ws;                   // 33.5M elems
  unsigned short* R2 = (unsigned short*)(ws + 67108864);      // 33.5M elems
  unsigned short* WB = (unsigned short*)(ws + 134217728);     // 2x1M elems
  unsigned short* R4 = (unsigned short*)(ws + 138412032);     // 33.5M elems

  const long PB = 2097152;   // proj per-batch elems (2048*1024)
  const long AB = 4194304;   // attn per-batch elems (2048*2048)

  // W -> bf16
  k_cvt<<<1024, 256, 0, stream>>>(Wimg, WB,           262144);
  k_cvt<<<1024, 256, 0, stream>>>(Wtxt, WB + 1048576, 262144);
  // LayerNorm -> bf16 norms in R1
  k_ln<<<16384, 256, 0, stream>>>(img, lnw, lnb, R1);
  k_ln<<<16384, 256, 0, stream>>>(txt, lnw, lnb, R1 + 16777216);
  // Projections: [16384,1024] = norm @ W^T + b  -> bf16 proj in R2
  k_gemm256<1><<<256, 512, 0, stream>>>(R1,            WB,           R2,            bimg, 1.f,
                                        1024, 1024, 1024, 1024, 0, 0, 0, 4, 64);
  k_gemm256<1><<<256, 512, 0, stream>>>(R1 + 16777216, WB + 1048576, R2 + 16777216, btxt, 1.f,
                                        1024, 1024, 1024, 1024, 0, 0, 0, 4, 64);
  // projT (per batch [1024][2048]) into R1 (norms dead)
  dim3 gt(16, 32, 8);
  k_transpose<<<gt, 256, 0, stream>>>(R2,            R1,            2048, 1024, PB, PB);
  k_transpose<<<gt, 256, 0, stream>>>(R2 + 16777216, R1 + 16777216, 2048, 1024, PB, PB);
  // logits[b] = proj_img[b] @ proj_txt[b]^T / 32  -> bf16 in R4
  k_gemm256<1><<<512, 512, 0, stream>>>(R2, R2 + 16777216, R4, nullptr, 0.03125f,
                                        1024, 1024, 1024, 2048, PB, PB, AB, 8, 8);
  // softmax rows, in place
  k_softmax<<<16384, 256, 0, stream>>>(R4);
  // attnT into R2 (proj dead)
  dim3 gat(32, 32, 8);
  k_transpose<<<gat, 256, 0, stream>>>(R4, R2, 2048, 2048, AB, AB);
  // image_out[b] = attn[b] @ txtpT[b]^T   (fp32 -> d_out)
  k_gemm256<0><<<256, 512, 0, stream>>>(R4, R1 + 16777216, out, nullptr, 1.f,
                                        2048, 2048, 2048, 1024, AB, PB, PB, 4, 8);
  // text_out[b] = attnT[b] @ imgpT[b]^T
  k_gemm256<0><<<256, 512, 0, stream>>>(R2, R1, out + 16777216, nullptr, 1.f,
                                        2048, 2048, 2048, 1024, AB, PB, PB, 4, 8);
}

// Round 4
// 422.670 us; speedup vs baseline: 1.2711x; 1.0403x over previous
//
#include <hip/hip_runtime.h>

// CrossAttention: LN -> proj GEMMs -> logits GEMM -> softmax -> 2 PV GEMMs.
// GEMM: 256x256 tile, BK=64, 8 waves (2Mx4N). 4 phases per K-tile, 2-buf LDS.
// LDS physical layout [buf][kk][16 windows][1024B]; window = 16 rows x 4
// chunks of one k-half, chunk (fr,q) at L=(fr>>1)*8+((q+4*(fr&1))^((fr>>1)&7))
// (bijective; read pattern isomorphic to the measured-0-conflict layout).
// Stage cadence per tile t: ph0 A(t+1,k1), ph1 B(t+1,k1), ph2 A(t+2,k0),
// ph3 B(t+2,k0) -- each issued right after its buffer region's last read.
// vmcnt(8) at ph1/ph3 ends (5-6 phase issue->consume distance, never 0
// except last-2-tile tail). Phase: {ds_read frags; stage; barrier;
// lgkmcnt(0); setprio(1); 16 MFMA; setprio(0); [wait]; barrier}.
// Workspace layout (196 MiB):
//   R1 [0,      64MiB): norm_img|norm_txt  -> reused as projT_img|projT_txt
//   R2 [64MiB, 128MiB): proj_img|proj_txt  -> reused as attnT
//   WB [128MiB,132MiB): W_img|W_txt as bf16
//   R4 [132MiB,196MiB): logits bf16 -> softmax in place -> attn

#define DEV __device__ __forceinline__

typedef short s16x8 __attribute__((ext_vector_type(8)));
typedef float f32x4 __attribute__((ext_vector_type(4)));

DEV unsigned short f2bf(float f){            // fp32 -> bf16, round-nearest-even
  unsigned u = __float_as_uint(f);
  u = (u + 0x7fffu + ((u >> 16) & 1u)) >> 16;
  return (unsigned short)u;
}
DEV float bf2f(unsigned short s){ return __uint_as_float(((unsigned)s) << 16); }

DEV void ldsload16(const void* g, void* l){
  __builtin_amdgcn_global_load_lds((const __attribute__((address_space(1))) void*)g,
                                   (__attribute__((address_space(3))) void*)l, 16, 0, 0);
}

// ---------------- fp32 -> bf16 convert ----------------
__global__ __launch_bounds__(256) void k_cvt(const float* __restrict__ src,
                                             unsigned short* __restrict__ dst, int n4){
  int i = blockIdx.x * 256 + threadIdx.x;
  if (i < n4){
    float4 v = ((const float4*)src)[i];
    ushort4 o;
    o.x = f2bf(v.x); o.y = f2bf(v.y); o.z = f2bf(v.z); o.w = f2bf(v.w);
    ((ushort4*)dst)[i] = o;
  }
}

// ---------------- LayerNorm (D=1024) fp32 -> bf16 ----------------
__global__ __launch_bounds__(256) void k_ln(const float* __restrict__ x,
                                            const float* __restrict__ w,
                                            const float* __restrict__ b,
                                            unsigned short* __restrict__ y){
  int row = blockIdx.x, tid = threadIdx.x;
  float4 v = ((const float4*)(x + (size_t)row * 1024))[tid];
  float s  = v.x + v.y + v.z + v.w;
  float s2 = v.x*v.x + v.y*v.y + v.z*v.z + v.w*v.w;
  #pragma unroll
  for (int o = 32; o > 0; o >>= 1){ s += __shfl_xor(s, o, 64); s2 += __shfl_xor(s2, o, 64); }
  __shared__ float sh[8];
  int wv = tid >> 6, ln = tid & 63;
  if (!ln){ sh[wv] = s; sh[4 + wv] = s2; }
  __syncthreads();
  s  = sh[0] + sh[1] + sh[2] + sh[3];
  s2 = sh[4] + sh[5] + sh[6] + sh[7];
  float mean = s * (1.f/1024.f);
  float var  = s2 * (1.f/1024.f) - mean * mean;
  float rstd = rsqrtf(var + 1e-5f);
  float4 w4 = ((const float4*)w)[tid];
  float4 b4 = ((const float4*)b)[tid];
  ushort4 o;
  o.x = f2bf((v.x-mean)*rstd*w4.x + b4.x);
  o.y = f2bf((v.y-mean)*rstd*w4.y + b4.y);
  o.z = f2bf((v.z-mean)*rstd*w4.z + b4.z);
  o.w = f2bf((v.w-mean)*rstd*w4.w + b4.w);
  ((ushort4*)(y + (size_t)row * 1024))[tid] = o;
}

// ---------------- bf16 B^T GEMM, 256x256, window-permuted deep pipeline ------
// C[m,n] = scale * sum_k A[m,k]*Bt[n,k] + bias[n].  Requires NT = K/64 >= 3.
// STG: stage one (matrix, tile T, k-half H): wave w fills windows w and w+8.
#define STG(MAT, BASE, LD, T, H) do{                                              \
  ldsload16((BASE) + (size_t)(wave*16 + sfr) * (LD) + (T)*64 + (H)*32 + sq*8,     \
            &MAT[(T)&1][H][wave][0]);                                             \
  ldsload16((BASE) + (size_t)(wave*16 + 128 + sfr) * (LD) + (T)*64 + (H)*32 + sq*8,\
            &MAT[(T)&1][H][wave + 8][0]);                                         \
}while(0)

template<int OUT_BF16>
__global__ __launch_bounds__(512, 2) void k_gemm256(const unsigned short* __restrict__ A,
                                                    const unsigned short* __restrict__ Bt,
                                                    void* __restrict__ C,
                                                    const float* __restrict__ bias, float scale,
                                                    int K, int lda, int ldb, int ldc,
                                                    long sA, long sB, long sC,
                                                    int NBX, int NBY){
  __shared__ __align__(16) unsigned short As[2][2][16][512];  // [buf][kk][win][1024B]
  __shared__ __align__(16) unsigned short Bs[2][2][16][512];
  int nwg = gridDim.x;                       // always a multiple of 8 here
  int bid = blockIdx.x;
  int swz = (bid & 7) * (nwg >> 3) + (bid >> 3);   // bijective XCD swizzle (T1)
  int bx = swz % NBX; int rem = swz / NBX;
  int by = rem % NBY; int bz = rem / NBY;

  int tid = threadIdx.x, lane = tid & 63, wave = tid >> 6;
  int wm = wave >> 2, wn = wave & 3;         // 2 x 4 wave grid
  int q = lane >> 4, fr = lane & 15;
  const unsigned short* Ab = A  + (size_t)bz * sA + (size_t)by * 256 * lda;
  const unsigned short* Bb = Bt + (size_t)bz * sB + (size_t)bx * 256 * ldb;
  // staging statics: lane writes window chunk `lane`; inverse of placement map
  int v   = (lane & 7) ^ ((lane >> 3) & 7);
  int sfr = 2 * (lane >> 3) + (v >> 2);      // source row within window (0..15)
  int sq  = v & 3;                           // source k-chunk within half (0..3)
  // read statics: placement of (fr, q) within a window, in shorts
  int roff = ((fr >> 1) << 6) + (((q + ((fr & 1) << 2)) ^ ((fr >> 1) & 7)) << 3);
  int NT = K >> 6;

  f32x4 acc[8][4];
  #pragma unroll
  for (int m = 0; m < 8; ++m)
    #pragma unroll
    for (int n = 0; n < 4; ++n) acc[m][n] = f32x4{0.f, 0.f, 0.f, 0.f};

  // prologue: (0,k0),(0,k1),(1,k0); force (0,k0), leave 8 in flight
  STG(As, Ab, lda, 0, 0); STG(Bs, Bb, ldb, 0, 0);
  STG(As, Ab, lda, 0, 1); STG(Bs, Bb, ldb, 0, 1);
  STG(As, Ab, lda, 1, 0); STG(Bs, Bb, ldb, 1, 0);
  asm volatile("s_waitcnt vmcnt(8)" ::: "memory");
  asm volatile("s_barrier" ::: "memory");

  for (int t = 0; t < NT; ++t){
    const int buf = t & 1;
    s16x8 bfr[4];
    #pragma unroll
    for (int ph = 0; ph < 4; ++ph){
      const int kk = ph >> 1;
      const unsigned short* Ah = &As[buf][kk][0][0];
      const unsigned short* Bh = &Bs[buf][kk][0][0];
      s16x8 af[4];
      if ((ph & 1) == 0){                    // new k-half: B frags + A m0-3
        #pragma unroll
        for (int n = 0; n < 4; ++n)  bfr[n] = *(const s16x8*)&Bh[(wn*4 + n)*512 + roff];
        #pragma unroll
        for (int mi = 0; mi < 4; ++mi) af[mi] = *(const s16x8*)&Ah[(wm*8 + mi)*512 + roff];
      } else {                               // A m4-7
        #pragma unroll
        for (int mi = 0; mi < 4; ++mi) af[mi] = *(const s16x8*)&Ah[(wm*8 + 4 + mi)*512 + roff];
      }
      if (ph == 0){ if (t + 1 < NT) STG(As, Ab, lda, t + 1, 1); }
      if (ph == 1){ if (t + 1 < NT) STG(Bs, Bb, ldb, t + 1, 1); }
      if (ph == 2){ if (t + 2 < NT) STG(As, Ab, lda, t + 2, 0); }
      if (ph == 3){ if (t + 2 < NT) STG(Bs, Bb, ldb, t + 2, 0); }
      asm volatile("s_barrier" ::: "memory");
      asm volatile("s_waitcnt lgkmcnt(0)" ::: "memory");
      __builtin_amdgcn_s_setprio(1);
      #pragma unroll
      for (int mi = 0; mi < 4; ++mi)
        #pragma unroll
        for (int n = 0; n < 4; ++n)
          acc[(ph&1)*4 + mi][n] = __builtin_amdgcn_mfma_f32_16x16x32_bf16(
              af[mi], bfr[n], acc[(ph&1)*4 + mi][n], 0, 0, 0);
      __builtin_amdgcn_s_setprio(0);
      if (ph & 1){                           // counted fence before closing barrier
        if (t + 2 < NT) asm volatile("s_waitcnt vmcnt(8)" ::: "memory");
        else            asm volatile("s_waitcnt vmcnt(0)" ::: "memory");
      }
      asm volatile("s_barrier" ::: "memory");
    }
  }
  // epilogue
  size_t cb = (size_t)bz * sC;
  int row0 = by*256 + wm*128 + q*4;
  int col0 = bx*256 + wn*64 + fr;
  #pragma unroll
  for (int m = 0; m < 8; ++m){
    #pragma unroll
    for (int n = 0; n < 4; ++n){
      int col = col0 + n*16;
      float bv = bias ? bias[col] : 0.f;
      #pragma unroll
      for (int j = 0; j < 4; ++j){
        int row = row0 + m*16 + j;
        float vv = acc[m][n][j] * scale + bv;
        if (OUT_BF16) ((unsigned short*)C)[cb + (size_t)row*ldc + col] = f2bf(vv);
        else          ((float*)C)[cb + (size_t)row*ldc + col] = vv;
      }
    }
  }
}

// ---------------- bf16 transpose, 64x64 tiles, swizzled LDS ----------------
__global__ __launch_bounds__(256) void k_transpose(const unsigned short* __restrict__ src,
                                                   unsigned short* __restrict__ dst,
                                                   int R, int C, long sS, long sD){
  __shared__ __align__(16) unsigned short tile[64 * 64];
  int tid = threadIdx.x;
  const unsigned short* sb = src + (size_t)blockIdx.z * sS;
  unsigned short* db = dst + (size_t)blockIdx.z * sD;
  int r0 = blockIdx.y * 64, c0 = blockIdx.x * 64;
  #pragma unroll
  for (int i = 0; i < 2; ++i){
    int ci = i * 256 + tid;
    int row = ci >> 3, cch = ci & 7;
    int pos = cch ^ (row & 7) ^ (row >> 3);
    uint4 v = *(const uint4*)&sb[(size_t)(r0 + row) * C + c0 + cch * 8];
    *(uint4*)&tile[row * 64 + pos * 8] = v;
  }
  __syncthreads();
  int ocp = tid >> 3, og = tid & 7;
  int oc = ocp * 2;
  union { uint4 v; unsigned short us[8]; } o0, o1;
  #pragma unroll
  for (int k = 0; k < 8; ++k){
    int r = og * 8 + k;
    int pos = (oc >> 3) ^ (r & 7) ^ (r >> 3);
    unsigned pr = *(const unsigned*)&tile[r * 64 + pos * 8 + (oc & 7)];
    o0.us[k] = (unsigned short)(pr & 0xffffu);
    o1.us[k] = (unsigned short)(pr >> 16);
  }
  *(uint4*)&db[(size_t)(c0 + oc    ) * R + r0 + og * 8] = o0.v;
  *(uint4*)&db[(size_t)(c0 + oc + 1) * R + r0 + og * 8] = o1.v;
}

// ---------------- row softmax over 2048, bf16 in-place ----------------
__global__ __launch_bounds__(256) void k_softmax(unsigned short* __restrict__ a){
  size_t row = blockIdx.x;
  unsigned short* p = a + row * 2048;
  int tid = threadIdx.x;
  union { uint4 v; unsigned short us[8]; } in, out;
  in.v = *(const uint4*)&p[tid * 8];
  float x[8];
  #pragma unroll
  for (int j = 0; j < 8; ++j) x[j] = bf2f(in.us[j]);
  float mx = x[0];
  #pragma unroll
  for (int j = 1; j < 8; ++j) mx = fmaxf(mx, x[j]);
  #pragma unroll
  for (int o = 32; o > 0; o >>= 1) mx = fmaxf(mx, __shfl_xor(mx, o, 64));
  __shared__ float sh[8];
  int wv = tid >> 6, ln = tid & 63;
  if (!ln) sh[wv] = mx;
  __syncthreads();
  mx = fmaxf(fmaxf(sh[0], sh[1]), fmaxf(sh[2], sh[3]));
  float sm = 0.f, e[8];
  #pragma unroll
  for (int j = 0; j < 8; ++j){ e[j] = __expf(x[j] - mx); sm += e[j]; }
  #pragma unroll
  for (int o = 32; o > 0; o >>= 1) sm += __shfl_xor(sm, o, 64);
  if (!ln) sh[4 + wv] = sm;
  __syncthreads();
  sm = sh[4] + sh[5] + sh[6] + sh[7];
  float inv = 1.f / sm;
  #pragma unroll
  for (int j = 0; j < 8; ++j) out.us[j] = f2bf(e[j] * inv);
  *(uint4*)&p[tid * 8] = out.v;
}

extern "C" void kernel_launch(void* const* d_in, const int* in_sizes, int n_in,
                              void* d_out, int out_size, void* d_ws, size_t ws_size,
                              hipStream_t stream) {
  const float* img  = (const float*)d_in[0];   // [8,2048,1024]
  const float* txt  = (const float*)d_in[1];   // [8,2048,1024]
  const float* lnw  = (const float*)d_in[2];   // [1024]
  const float* lnb  = (const float*)d_in[3];   // [1024]
  const float* Wimg = (const float*)d_in[4];   // [1024,1024]
  const float* bimg = (const float*)d_in[5];   // [1024]
  const float* Wtxt = (const float*)d_in[6];   // [1024,1024]
  const float* btxt = (const float*)d_in[7];   // [1024]
  float* out = (float*)d_out;                  // image_out | text_out

  char* ws = (char*)d_ws;
  unsigned short* R1 = (unsigned short*)ws;                   // 33.5M elems
  unsigned short* R2 = (unsigned short*)(ws + 67108864);      // 33.5M elems
  unsigned short* WB = (unsigned short*)(ws + 134217728);     // 2x1M elems
  unsigned short* R4 = (unsigned short*)(ws + 138412032);     // 33.5M elems

  const long PB = 2097152;   // proj per-batch elems (2048*1024)
  const long AB = 4194304;   // attn per-batch elems (2048*2048)

  // W -> bf16
  k_cvt<<<1024, 256, 0, stream>>>(Wimg, WB,           262144);
  k_cvt<<<1024, 256, 0, stream>>>(Wtxt, WB + 1048576, 262144);
  // LayerNorm -> bf16 norms in R1
  k_ln<<<16384, 256, 0, stream>>>(img, lnw, lnb, R1);
  k_ln<<<16384, 256, 0, stream>>>(txt, lnw, lnb, R1 + 16777216);
  // Projections: [16384,1024] = norm @ W^T + b  -> bf16 proj in R2
  k_gemm256<1><<<256, 512, 0, stream>>>(R1,            WB,           R2,            bimg, 1.f,
                                        1024, 1024, 1024, 1024, 0, 0, 0, 4, 64);
  k_gemm256<1><<<256, 512, 0, stream>>>(R1 + 16777216, WB + 1048576, R2 + 16777216, btxt, 1.f,
                                        1024, 1024, 1024, 1024, 0, 0, 0, 4, 64);
  // projT (per batch [1024][2048]) into R1 (norms dead)
  dim3 gt(16, 32, 8);
  k_transpose<<<gt, 256, 0, stream>>>(R2,            R1,            2048, 1024, PB, PB);
  k_transpose<<<gt, 256, 0, stream>>>(R2 + 16777216, R1 + 16777216, 2048, 1024, PB, PB);
  // logits[b] = proj_img[b] @ proj_txt[b]^T / 32  -> bf16 in R4
  k_gemm256<1><<<512, 512, 0, stream>>>(R2, R2 + 16777216, R4, nullptr, 0.03125f,
                                        1024, 1024, 1024, 2048, PB, PB, AB, 8, 8);
  // softmax rows, in place
  k_softmax<<<16384, 256, 0, stream>>>(R4);
  // attnT into R2 (proj dead)
  dim3 gat(32, 32, 8);
  k_transpose<<<gat, 256, 0, stream>>>(R4, R2, 2048, 2048, AB, AB);
  // image_out[b] = attn[b] @ txtpT[b]^T   (fp32 -> d_out)
  k_gemm256<0><<<256, 512, 0, stream>>>(R4, R1 + 16777216, out, nullptr, 1.f,
                                        2048, 2048, 2048, 1024, AB, PB, PB, 4, 8);
  // text_out[b] = attnT[b] @ imgpT[b]^T
  k_gemm256<0><<<256, 512, 0, stream>>>(R2, R1, out + 16777216, nullptr, 1.f,
                                        2048, 2048, 2048, 1024, AB, PB, PB, 4, 8);
}